// Round 3
// baseline (647.858 us; speedup 1.0000x reference)
//
#include <hip/hip_runtime.h>
#include <hip/hip_bf16.h>

#define NB 2
#define NL 2048
#define NH 12
#define ND 64
#define NEWTON 6

typedef __bf16 bf16x8 __attribute__((ext_vector_type(8)));
typedef __bf16 bf16x4 __attribute__((ext_vector_type(4)));
typedef float f32x4 __attribute__((ext_vector_type(4)));

__device__ __forceinline__ void split_bf16(float f, __bf16& hi, __bf16& lo) {
  __bf16 h = (__bf16)f;
  hi = h;
  lo = (__bf16)(f - (float)h);
}

// ------- kernel 0: V [B,L,H,D](fp32) -> Vt_hi/Vt_lo [B,H,D,L](bf16 planes) -------
__global__ void transpose_v(const float* __restrict__ v,
                            __bf16* __restrict__ vt_hi,
                            __bf16* __restrict__ vt_lo) {
  __shared__ float tile[64][65];  // +1 pad
  const int blk = blockIdx.x;
  const int kt = blk & 31;            // L/64 = 32 key tiles
  const int h = (blk >> 5) % NH;
  const int b = blk / (32 * NH);
  const int t = threadIdx.x;
  const int sub = t >> 4;             // 0..15
  const int c4 = (t & 15) * 4;
#pragma unroll
  for (int rr = 0; rr < 4; ++rr) {
    int k = rr * 16 + sub;
    int off = ((b * NL + kt * 64 + k) * NH + h) * ND + c4;
    f32x4 val = *(const f32x4*)(v + off);
    tile[c4 + 0][k] = val[0];
    tile[c4 + 1][k] = val[1];
    tile[c4 + 2][k] = val[2];
    tile[c4 + 3][k] = val[3];
  }
  __syncthreads();
#pragma unroll
  for (int rr = 0; rr < 4; ++rr) {
    int d = rr * 16 + sub;
    int off = ((b * NH + h) * ND + d) * NL + kt * 64 + c4;
    bf16x4 hv, lv;
#pragma unroll
    for (int i = 0; i < 4; ++i) {
      __bf16 hb, lb;
      split_bf16(tile[d][c4 + i], hb, lb);
      hv[i] = hb;
      lv[i] = lb;
    }
    *(bf16x4*)(vt_hi + off) = hv;
    *(bf16x4*)(vt_lo + off) = lv;
  }
}

// ---------------- main fused attention-poly kernel ----------------
// Block = 1024 threads = 16 waves, owns one 16-query tile of one (b,h).
// Wave w owns key tiles {w + 16t, t=0..7}; scores live in registers in MFMA
// C-layout: sc[t][r] = S[row = quad*4+r][key = (w+16t)*16 + l16].
__launch_bounds__(1024)
__global__ void attn_poly(const float* __restrict__ qg,
                          const float* __restrict__ kg,
                          const __bf16* __restrict__ vtg_hi,
                          const __bf16* __restrict__ vtg_lo,
                          float* __restrict__ outg) {
  __shared__ __align__(16) float slab[16 * 16 * 36];  // per-wave slabs; aliased as O-reduce tree
  __shared__ float redps[16][16];
  __shared__ float redpsd[16][16];
  __shared__ float cbuf[16];

  const int tid = threadIdx.x;
  const int w = tid >> 6;
  const int lane = tid & 63;
  const int quad = lane >> 4;
  const int l16 = lane & 15;

  const int blk = blockIdx.x;
  const int qt = blk & 127;      // qt inner => 128 consecutive blocks share (b,h) K/V in L2
  const int bh = blk >> 7;
  const int h = bh % NH;
  const int b = bh / NH;
  const int qbase = qt * 16;

  // ---- Q fragments fp32 -> bf16 hi/lo (A-operand: m = l16, k = quad*8 + j) ----
  bf16x8 qhi0, qlo0, qhi1, qlo1;
  {
    const float* qp = qg + ((b * NL + qbase + l16) * NH + h) * ND + quad * 8;
    f32x4 a0 = *(const f32x4*)(qp);
    f32x4 a1 = *(const f32x4*)(qp + 4);
    f32x4 a2 = *(const f32x4*)(qp + 32);
    f32x4 a3 = *(const f32x4*)(qp + 36);
#pragma unroll
    for (int j = 0; j < 4; ++j) {
      __bf16 hb, lb;
      split_bf16(a0[j], hb, lb); qhi0[j] = hb;     qlo0[j] = lb;
      split_bf16(a1[j], hb, lb); qhi0[4 + j] = hb; qlo0[4 + j] = lb;
      split_bf16(a2[j], hb, lb); qhi1[j] = hb;     qlo1[j] = lb;
      split_bf16(a3[j], hb, lb); qhi1[4 + j] = hb; qlo1[4 + j] = lb;
    }
  }

  // ---- phase 1: S = (Q Kt)/8 via hi/lo-split MFMA (lo*lo dropped) ----
  float sc[8][4];
  {
    const float* kb = kg + (b * NL * NH + h) * ND;
#pragma unroll
    for (int t = 0; t < 8; ++t) {
      int key = (w + 16 * t) * 16 + l16;
      const float* kp = kb + key * (NH * ND) + quad * 8;
      f32x4 b0 = *(const f32x4*)(kp);
      f32x4 b1 = *(const f32x4*)(kp + 4);
      f32x4 b2 = *(const f32x4*)(kp + 32);
      f32x4 b3 = *(const f32x4*)(kp + 36);
      bf16x8 khi0, klo0, khi1, klo1;
#pragma unroll
      for (int j = 0; j < 4; ++j) {
        __bf16 hb, lb;
        split_bf16(b0[j], hb, lb); khi0[j] = hb;     klo0[j] = lb;
        split_bf16(b1[j], hb, lb); khi0[4 + j] = hb; klo0[4 + j] = lb;
        split_bf16(b2[j], hb, lb); khi1[j] = hb;     klo1[j] = lb;
        split_bf16(b3[j], hb, lb); khi1[4 + j] = hb; klo1[4 + j] = lb;
      }
      f32x4 acc = {0.f, 0.f, 0.f, 0.f};
      acc = __builtin_amdgcn_mfma_f32_16x16x32_bf16(qhi0, khi0, acc, 0, 0, 0);
      acc = __builtin_amdgcn_mfma_f32_16x16x32_bf16(qhi1, khi1, acc, 0, 0, 0);
      acc = __builtin_amdgcn_mfma_f32_16x16x32_bf16(qhi0, klo0, acc, 0, 0, 0);
      acc = __builtin_amdgcn_mfma_f32_16x16x32_bf16(qhi1, klo1, acc, 0, 0, 0);
      acc = __builtin_amdgcn_mfma_f32_16x16x32_bf16(qlo0, khi0, acc, 0, 0, 0);
      acc = __builtin_amdgcn_mfma_f32_16x16x32_bf16(qlo1, khi1, acc, 0, 0, 0);
#pragma unroll
      for (int r = 0; r < 4; ++r) sc[t][r] = acc[r] * 0.125f;
    }
  }

  // ---- phase 2: row max -> c0 = -max - 1 ----
  {
    float mx[4];
#pragma unroll
    for (int r = 0; r < 4; ++r) {
      float m = sc[0][r];
#pragma unroll
      for (int t = 1; t < 8; ++t) m = fmaxf(m, sc[t][r]);
      mx[r] = m;
    }
#pragma unroll
    for (int off = 1; off < 16; off <<= 1) {
#pragma unroll
      for (int r = 0; r < 4; ++r) mx[r] = fmaxf(mx[r], __shfl_xor(mx[r], off, 16));
    }
    if (l16 < 4) {
      float v = (l16 == 0) ? mx[0] : (l16 == 1) ? mx[1] : (l16 == 2) ? mx[2] : mx[3];
      redps[w][quad * 4 + l16] = v;
    }
  }
  __syncthreads();
  if (tid < 16) {
    float m = redps[0][tid];
#pragma unroll
    for (int i = 1; i < 16; ++i) m = fmaxf(m, redps[i][tid]);
    cbuf[tid] = -m - 1.0f;
  }
  __syncthreads();

  // ---- phase 3: Newton x6 on c:  c -= (Sum y^-2 - 1) / (2 Sum y^-3 + eps) ----
  for (int it = 0; it < NEWTON; ++it) {
    float cr[4];
#pragma unroll
    for (int r = 0; r < 4; ++r) cr[r] = cbuf[quad * 4 + r];
    float ps[4] = {0.f, 0.f, 0.f, 0.f};
    float psd[4] = {0.f, 0.f, 0.f, 0.f};
#pragma unroll
    for (int t = 0; t < 8; ++t) {
#pragma unroll
      for (int r = 0; r < 4; ++r) {
        float y = -(sc[t][r] + cr[r]);          // y >= 1 when layout correct
        y = fmaxf(y, 0.25f);                    // NaN-proofing (no-op when correct)
        float r1 = __builtin_amdgcn_rcpf(y);
        float r2 = r1 * r1;
        ps[r] += r2;
        psd[r] += r2 * r1;
      }
    }
#pragma unroll
    for (int off = 1; off < 16; off <<= 1) {
#pragma unroll
      for (int r = 0; r < 4; ++r) {
        ps[r] += __shfl_xor(ps[r], off, 16);
        psd[r] += __shfl_xor(psd[r], off, 16);
      }
    }
    if (l16 < 4) {
      float a = (l16 == 0) ? ps[0] : (l16 == 1) ? ps[1] : (l16 == 2) ? ps[2] : ps[3];
      float d = (l16 == 0) ? psd[0] : (l16 == 1) ? psd[1] : (l16 == 2) ? psd[2] : psd[3];
      redps[w][quad * 4 + l16] = a;
      redpsd[w][quad * 4 + l16] = d;
    }
    __syncthreads();
    if (tid < 16) {
      float pst = 0.f, psdt = 0.f;
#pragma unroll
      for (int i = 0; i < 16; ++i) { pst += redps[i][tid]; psdt += redpsd[i][tid]; }
      cbuf[tid] -= (pst - 1.0f) / (2.0f * psdt + 1e-8f);
    }
    __syncthreads();
  }

  // ---- phase 4: weights w = 1/y^2 (overwrite sc) ----
  {
    float cr[4];
#pragma unroll
    for (int r = 0; r < 4; ++r) cr[r] = cbuf[quad * 4 + r];
#pragma unroll
    for (int t = 0; t < 8; ++t) {
#pragma unroll
      for (int r = 0; r < 4; ++r) {
        float y = -(sc[t][r] + cr[r]);
        y = fmaxf(y, 0.25f);                    // NaN-proofing (no-op when correct)
        float r1 = __builtin_amdgcn_rcpf(y);
        sc[t][r] = r1 * r1;
      }
    }
  }

  // ---- phase 5: O_partial = W * V (W hi/lo x V hi, plus W hi x V lo) ----
  f32x4 oacc[4];
#pragma unroll
  for (int n = 0; n < 4; ++n) oacc[n] = (f32x4){0.f, 0.f, 0.f, 0.f};
  float* myslab = slab + w * (16 * 36);
  const __bf16* vtb_hi = vtg_hi + (b * NH + h) * (ND * NL);
  const __bf16* vtb_lo = vtg_lo + (b * NH + h) * (ND * NL);
#pragma unroll
  for (int p = 0; p < 4; ++p) {
    const int kt0 = w + 16 * (2 * p);
    const int kt1 = w + 16 * (2 * p + 1);
    // write two 16x16 C-layout weight tiles into the wave-private slab
#pragma unroll
    for (int ts = 0; ts < 2; ++ts) {
      const int t = 2 * p + ts;
#pragma unroll
      for (int r = 0; r < 4; ++r)
        myslab[(quad * 4 + r) * 36 + ts * 16 + l16] = sc[t][r];
    }
    __syncthreads();
    // read back in A-layout: row m = l16, k = quad*8 + j (8 consecutive fp32)
    float wv[8];
    *(f32x4*)(&wv[0]) = *(const f32x4*)(myslab + l16 * 36 + quad * 8);
    *(f32x4*)(&wv[4]) = *(const f32x4*)(myslab + l16 * 36 + quad * 8 + 4);
    bf16x8 ahi, alo;
#pragma unroll
    for (int j = 0; j < 8; ++j) {
      __bf16 hb, lb;
      split_bf16(wv[j], hb, lb);
      ahi[j] = hb;
      alo[j] = lb;
    }
    const int keystart = (quad < 2) ? (kt0 * 16 + quad * 8)
                                    : (kt1 * 16 + (quad - 2) * 8);
#pragma unroll
    for (int n = 0; n < 4; ++n) {
      const __bf16* bph = vtb_hi + (n * 16 + l16) * NL + keystart;
      const __bf16* bpl = vtb_lo + (n * 16 + l16) * NL + keystart;
      bf16x8 bh = *(const bf16x8*)bph;
      bf16x8 bl = *(const bf16x8*)bpl;
      oacc[n] = __builtin_amdgcn_mfma_f32_16x16x32_bf16(ahi, bh, oacc[n], 0, 0, 0);
      oacc[n] = __builtin_amdgcn_mfma_f32_16x16x32_bf16(alo, bh, oacc[n], 0, 0, 0);
      oacc[n] = __builtin_amdgcn_mfma_f32_16x16x32_bf16(ahi, bl, oacc[n], 0, 0, 0);
    }
    __syncthreads();  // protect slab from next iteration's writes
  }

  // ---- phase 6: tree-reduce the 16 per-wave partial O tiles (alias slab) ----
  __syncthreads();
  float* tree = slab;  // [src][16][68]: 8*16*68 = 8704 floats <= 9216 (slab)
  for (int s = 8; s >= 1; s >>= 1) {
    if (w >= s && w < 2 * s) {
      float* dst = tree + (w - s) * (16 * 68);
#pragma unroll
      for (int n = 0; n < 4; ++n)
#pragma unroll
        for (int r = 0; r < 4; ++r)
          dst[(quad * 4 + r) * 68 + n * 16 + l16] = oacc[n][r];
    }
    __syncthreads();
    if (w < s) {
      const float* src = tree + w * (16 * 68);
#pragma unroll
      for (int n = 0; n < 4; ++n)
#pragma unroll
        for (int r = 0; r < 4; ++r)
          oacc[n][r] += src[(quad * 4 + r) * 68 + n * 16 + l16];
    }
    __syncthreads();
  }

  // ---- epilogue: wave 0 writes O[b, q, h, d] as fp32 ----
  if (w == 0) {
#pragma unroll
    for (int n = 0; n < 4; ++n) {
#pragma unroll
      for (int r = 0; r < 4; ++r) {
        int off = ((b * NL + qbase + quad * 4 + r) * NH + h) * ND + n * 16 + l16;
        outg[off] = oacc[n][r];
      }
    }
  }
}

extern "C" void kernel_launch(void* const* d_in, const int* in_sizes, int n_in,
                              void* d_out, int out_size, void* d_ws, size_t ws_size,
                              hipStream_t stream) {
  const float* q = (const float*)d_in[0];
  const float* k = (const float*)d_in[1];
  const float* v = (const float*)d_in[2];

  const size_t plane = (size_t)NB * NH * ND * NL;
  __bf16* vt_hi = (__bf16*)d_ws;            // 6.29 MB
  __bf16* vt_lo = vt_hi + plane;            // 6.29 MB

  transpose_v<<<NB * NH * (NL / 64), 256, 0, stream>>>(v, vt_hi, vt_lo);

  attn_poly<<<NB * NH * (NL / 16), 1024, 0, stream>>>(
      q, k, vt_hi, vt_lo, (float*)d_out);
}

// Round 4
// 488.613 us; speedup vs baseline: 1.3259x; 1.3259x over previous
//
#include <hip/hip_runtime.h>
#include <hip/hip_bf16.h>

#define NB 2
#define NL 2048
#define NH 12
#define ND 64
#define NEWTON 6
#define WV 8            // waves per block
#define TPW 16          // key-tiles per wave = 128/WV

typedef __bf16 bf16x8 __attribute__((ext_vector_type(8)));
typedef __bf16 bf16x4 __attribute__((ext_vector_type(4)));
typedef float f32x4 __attribute__((ext_vector_type(4)));

__device__ __forceinline__ void split_bf16(float f, __bf16& hi, __bf16& lo) {
  __bf16 h = (__bf16)f;
  hi = h;
  lo = (__bf16)(f - (float)h);
}

// ---- kernel A: K [B,L,H,D](fp32) -> Khi/Klo [B,H,L,D](bf16 planes) ----
__global__ void split_k(const float* __restrict__ k,
                        __bf16* __restrict__ khi,
                        __bf16* __restrict__ klo) {
  const int blk = blockIdx.x;
  const int kt = blk & 31;
  const int h = (blk >> 5) % NH;
  const int b = blk / (32 * NH);
  const int t = threadIdx.x;
  const int sub = t >> 4;
  const int d4 = (t & 15) * 4;
#pragma unroll
  for (int rr = 0; rr < 4; ++rr) {
    int key = kt * 64 + rr * 16 + sub;
    int ioff = ((b * NL + key) * NH + h) * ND + d4;
    int ooff = ((b * NH + h) * NL + key) * ND + d4;
    f32x4 val = *(const f32x4*)(k + ioff);
    bf16x4 hv, lv;
#pragma unroll
    for (int i = 0; i < 4; ++i) {
      __bf16 hb, lb;
      split_bf16(val[i], hb, lb);
      hv[i] = hb;
      lv[i] = lb;
    }
    *(bf16x4*)(khi + ooff) = hv;
    *(bf16x4*)(klo + ooff) = lv;
  }
}

// ---- kernel B: V [B,L,H,D](fp32) -> Vt_hi/Vt_lo [B,H,D,L](bf16 planes) ----
__global__ void transpose_v(const float* __restrict__ v,
                            __bf16* __restrict__ vt_hi,
                            __bf16* __restrict__ vt_lo) {
  __shared__ float tile[64][65];
  const int blk = blockIdx.x;
  const int kt = blk & 31;
  const int h = (blk >> 5) % NH;
  const int b = blk / (32 * NH);
  const int t = threadIdx.x;
  const int sub = t >> 4;
  const int c4 = (t & 15) * 4;
#pragma unroll
  for (int rr = 0; rr < 4; ++rr) {
    int k = rr * 16 + sub;
    int off = ((b * NL + kt * 64 + k) * NH + h) * ND + c4;
    f32x4 val = *(const f32x4*)(v + off);
    tile[c4 + 0][k] = val[0];
    tile[c4 + 1][k] = val[1];
    tile[c4 + 2][k] = val[2];
    tile[c4 + 3][k] = val[3];
  }
  __syncthreads();
#pragma unroll
  for (int rr = 0; rr < 4; ++rr) {
    int d = rr * 16 + sub;
    int off = ((b * NH + h) * ND + d) * NL + kt * 64 + c4;
    bf16x4 hv, lv;
#pragma unroll
    for (int i = 0; i < 4; ++i) {
      __bf16 hb, lb;
      split_bf16(tile[d][c4 + i], hb, lb);
      hv[i] = hb;
      lv[i] = lb;
    }
    *(bf16x4*)(vt_hi + off) = hv;
    *(bf16x4*)(vt_lo + off) = lv;
  }
}

// ---------------- main fused attention-poly kernel ----------------
// Block = 512 threads = 8 waves, one 16-query tile of one (b,h).
// Wave w owns key-tiles {w + 8t, t=0..15}; scores in registers, MFMA C-layout:
// sc[t][r] = S[row = quad*4+r][key = (w+8t)*16 + l16].
// Per-lane c for row (lane&15), redundantly maintained by all waves.
__launch_bounds__(512, 4)
__global__ void attn_poly(const float* __restrict__ qg,
                          const __bf16* __restrict__ khig,
                          const __bf16* __restrict__ klog,
                          const __bf16* __restrict__ vtg_hi,
                          const __bf16* __restrict__ vtg_lo,
                          float* __restrict__ outg) {
  __shared__ __align__(16) float ex[WV][16][68];  // phase5 slabs + phase6 partials
  __shared__ float redmax[WV][16];
  __shared__ float redps[2][WV][16];
  __shared__ float redpsd[2][WV][16];

  const int tid = threadIdx.x;
  const int w = tid >> 6;
  const int lane = tid & 63;
  const int quad = lane >> 4;
  const int l16 = lane & 15;

  const int blk = blockIdx.x;
  const int qt = blk & 127;        // qt inner: 128 consecutive blocks share (b,h)
  const int bh = blk >> 7;
  const int h = bh % NH;
  const int b = bh / NH;
  const int qbase = qt * 16;

  // ---- Q fragments fp32 -> bf16 hi/lo (A-operand: m = l16, k = quad*8 + j) ----
  bf16x8 qhi0, qlo0, qhi1, qlo1;
  {
    const float* qp = qg + ((b * NL + qbase + l16) * NH + h) * ND + quad * 8;
    f32x4 a0 = *(const f32x4*)(qp);
    f32x4 a1 = *(const f32x4*)(qp + 4);
    f32x4 a2 = *(const f32x4*)(qp + 32);
    f32x4 a3 = *(const f32x4*)(qp + 36);
#pragma unroll
    for (int j = 0; j < 4; ++j) {
      __bf16 hb, lb;
      split_bf16(a0[j], hb, lb); qhi0[j] = hb;     qlo0[j] = lb;
      split_bf16(a1[j], hb, lb); qhi0[4 + j] = hb; qlo0[4 + j] = lb;
      split_bf16(a2[j], hb, lb); qhi1[j] = hb;     qlo1[j] = lb;
      split_bf16(a3[j], hb, lb); qhi1[4 + j] = hb; qlo1[4 + j] = lb;
    }
  }

  // ---- phase 1: S = (Q Kt)/8 via hi/lo-split MFMA (pre-split K planes) ----
  float sc[TPW][4];
  {
    const __bf16* kbh = khig + (size_t)(b * NH + h) * NL * ND;
    const __bf16* kbl = klog + (size_t)(b * NH + h) * NL * ND;
#pragma unroll
    for (int t = 0; t < TPW; ++t) {
      int key = (w + WV * t) * 16 + l16;
      const __bf16* kph = kbh + key * ND + quad * 8;
      const __bf16* kpl = kbl + key * ND + quad * 8;
      bf16x8 khi0 = *(const bf16x8*)kph;
      bf16x8 khi1 = *(const bf16x8*)(kph + 32);
      bf16x8 klo0 = *(const bf16x8*)kpl;
      bf16x8 klo1 = *(const bf16x8*)(kpl + 32);
      f32x4 acc = {0.f, 0.f, 0.f, 0.f};
      acc = __builtin_amdgcn_mfma_f32_16x16x32_bf16(qhi0, khi0, acc, 0, 0, 0);
      acc = __builtin_amdgcn_mfma_f32_16x16x32_bf16(qhi1, khi1, acc, 0, 0, 0);
      acc = __builtin_amdgcn_mfma_f32_16x16x32_bf16(qhi0, klo0, acc, 0, 0, 0);
      acc = __builtin_amdgcn_mfma_f32_16x16x32_bf16(qhi1, klo1, acc, 0, 0, 0);
      acc = __builtin_amdgcn_mfma_f32_16x16x32_bf16(qlo0, khi0, acc, 0, 0, 0);
      acc = __builtin_amdgcn_mfma_f32_16x16x32_bf16(qlo1, khi1, acc, 0, 0, 0);
#pragma unroll
      for (int r = 0; r < 4; ++r) sc[t][r] = acc[r] * 0.125f;
    }
  }

  // ---- phase 2: row max -> per-lane c = -max(row=l16) - 1 ----
  float cv;  // c for row (lane & 15), redundant across quads & waves
  {
    float mx[4];
#pragma unroll
    for (int r = 0; r < 4; ++r) {
      float m = sc[0][r];
#pragma unroll
      for (int t = 1; t < TPW; ++t) m = fmaxf(m, sc[t][r]);
      mx[r] = m;
    }
#pragma unroll
    for (int off = 1; off < 16; off <<= 1) {
#pragma unroll
      for (int r = 0; r < 4; ++r) mx[r] = fmaxf(mx[r], __shfl_xor(mx[r], off, 16));
    }
    if (l16 < 4) {
      float v = (l16 == 0) ? mx[0] : (l16 == 1) ? mx[1] : (l16 == 2) ? mx[2] : mx[3];
      redmax[w][quad * 4 + l16] = v;
    }
    __syncthreads();
    float m = redmax[0][l16];
#pragma unroll
    for (int i = 1; i < WV; ++i) m = fmaxf(m, redmax[i][l16]);
    cv = -m - 1.0f;
  }

  // ---- phase 3: Newton x6, one barrier per iter, no serial section ----
  for (int it = 0; it < NEWTON; ++it) {
    const int par = it & 1;
    float cr[4];
#pragma unroll
    for (int r = 0; r < 4; ++r)
      cr[r] = __shfl(cv, (lane & ~15) | (quad * 4 + r), 64);
    float ps[4] = {0.f, 0.f, 0.f, 0.f};
    float psd[4] = {0.f, 0.f, 0.f, 0.f};
#pragma unroll
    for (int t = 0; t < TPW; ++t) {
#pragma unroll
      for (int r = 0; r < 4; ++r) {
        float y = -(sc[t][r] + cr[r]);
        y = fmaxf(y, 0.25f);                     // no-op when invariant holds
        float r1 = __builtin_amdgcn_rcpf(y);
        float r2 = r1 * r1;
        ps[r] += r2;
        psd[r] += r2 * r1;
      }
    }
#pragma unroll
    for (int off = 1; off < 16; off <<= 1) {
#pragma unroll
      for (int r = 0; r < 4; ++r) {
        ps[r] += __shfl_xor(ps[r], off, 16);
        psd[r] += __shfl_xor(psd[r], off, 16);
      }
    }
    if (l16 < 4) {
      float a = (l16 == 0) ? ps[0] : (l16 == 1) ? ps[1] : (l16 == 2) ? ps[2] : ps[3];
      float d = (l16 == 0) ? psd[0] : (l16 == 1) ? psd[1] : (l16 == 2) ? psd[2] : psd[3];
      redps[par][w][quad * 4 + l16] = a;
      redpsd[par][w][quad * 4 + l16] = d;
    }
    __syncthreads();
    float pst = 0.f, psdt = 0.f;
#pragma unroll
    for (int i = 0; i < WV; ++i) {
      pst += redps[par][i][l16];
      psdt += redpsd[par][i][l16];
    }
    cv -= (pst - 1.0f) / (2.0f * psdt + 1e-8f);   // identical in all redundant lanes
  }

  // ---- phase 4: weights = 1/y^2 (overwrite sc) ----
  {
    float cr[4];
#pragma unroll
    for (int r = 0; r < 4; ++r)
      cr[r] = __shfl(cv, (lane & ~15) | (quad * 4 + r), 64);
#pragma unroll
    for (int t = 0; t < TPW; ++t) {
#pragma unroll
      for (int r = 0; r < 4; ++r) {
        float y = -(sc[t][r] + cr[r]);
        y = fmaxf(y, 0.25f);
        float r1 = __builtin_amdgcn_rcpf(y);
        sc[t][r] = r1 * r1;
      }
    }
  }

  // ---- phase 5: O_partial = W * V ; wave-private LDS slab, no block barriers ----
  f32x4 oacc[4];
#pragma unroll
  for (int n = 0; n < 4; ++n) oacc[n] = (f32x4){0.f, 0.f, 0.f, 0.f};
  float* myslab = &ex[w][0][0];                   // 16 rows x 68 stride
  const __bf16* vtb_hi = vtg_hi + (size_t)(b * NH + h) * ND * NL;
  const __bf16* vtb_lo = vtg_lo + (size_t)(b * NH + h) * ND * NL;
#pragma unroll
  for (int p = 0; p < 8; ++p) {
    const int kt0 = w + WV * (2 * p);
    const int kt1 = w + WV * (2 * p + 1);
#pragma unroll
    for (int ts = 0; ts < 2; ++ts) {
      const int t = 2 * p + ts;
#pragma unroll
      for (int r = 0; r < 4; ++r)
        myslab[(quad * 4 + r) * 68 + ts * 16 + l16] = sc[t][r];
    }
    asm volatile("s_waitcnt lgkmcnt(0)" ::: "memory");  // wave-internal exchange
    float wv8[8];
    *(f32x4*)(&wv8[0]) = *(const f32x4*)(myslab + l16 * 68 + quad * 8);
    *(f32x4*)(&wv8[4]) = *(const f32x4*)(myslab + l16 * 68 + quad * 8 + 4);
    bf16x8 ahi, alo;
#pragma unroll
    for (int j = 0; j < 8; ++j) {
      __bf16 hb, lb;
      split_bf16(wv8[j], hb, lb);
      ahi[j] = hb;
      alo[j] = lb;
    }
    const int keystart = (quad < 2) ? (kt0 * 16 + quad * 8)
                                    : (kt1 * 16 + (quad - 2) * 8);
#pragma unroll
    for (int n = 0; n < 4; ++n) {
      const __bf16* bph = vtb_hi + (n * 16 + l16) * NL + keystart;
      const __bf16* bpl = vtb_lo + (n * 16 + l16) * NL + keystart;
      bf16x8 bhv = *(const bf16x8*)bph;
      bf16x8 blv = *(const bf16x8*)bpl;
      oacc[n] = __builtin_amdgcn_mfma_f32_16x16x32_bf16(ahi, bhv, oacc[n], 0, 0, 0);
      oacc[n] = __builtin_amdgcn_mfma_f32_16x16x32_bf16(alo, bhv, oacc[n], 0, 0, 0);
      oacc[n] = __builtin_amdgcn_mfma_f32_16x16x32_bf16(ahi, blv, oacc[n], 0, 0, 0);
    }
    asm volatile("s_waitcnt lgkmcnt(0)" ::: "memory");  // reads done before reuse
  }

  // ---- phase 6: store partials, one barrier, gather+sum, write global ----
#pragma unroll
  for (int n = 0; n < 4; ++n)
#pragma unroll
    for (int r = 0; r < 4; ++r)
      ex[w][quad * 4 + r][n * 16 + l16] = oacc[n][r];
  __syncthreads();
  {
    const int row = 2 * w + (lane >> 5);
    const int d = lane & 31;
    float v0 = 0.f, v1 = 0.f;
#pragma unroll
    for (int i = 0; i < WV; ++i) {
      v0 += ex[i][row][d];
      v1 += ex[i][row][d + 32];
    }
    const int off = ((b * NL + qbase + row) * NH + h) * ND + d;
    outg[off] = v0;
    outg[off + 32] = v1;
  }
}

extern "C" void kernel_launch(void* const* d_in, const int* in_sizes, int n_in,
                              void* d_out, int out_size, void* d_ws, size_t ws_size,
                              hipStream_t stream) {
  const float* q = (const float*)d_in[0];
  const float* k = (const float*)d_in[1];
  const float* v = (const float*)d_in[2];

  const size_t plane = (size_t)NB * NH * ND * NL;  // 3.15M elems, 6.29MB/plane
  __bf16* k_hi = (__bf16*)d_ws;
  __bf16* k_lo = k_hi + plane;
  __bf16* vt_hi = k_lo + plane;
  __bf16* vt_lo = vt_hi + plane;

  split_k<<<NB * NH * (NL / 64), 256, 0, stream>>>(k, k_hi, k_lo);
  transpose_v<<<NB * NH * (NL / 64), 256, 0, stream>>>(v, vt_hi, vt_lo);

  attn_poly<<<NB * NH * (NL / 16), 512, 0, stream>>>(
      q, k_hi, k_lo, vt_hi, vt_lo, (float*)d_out);
}